// Round 1
// baseline (596.882 us; speedup 1.0000x reference)
//
#include <hip/hip_runtime.h>
#include <hip/hip_bf16.h>

#define TT 8192
#define DD 2048
#define OO 2048
#define EE 8

typedef __attribute__((ext_vector_type(4))) float f32x4;
typedef __attribute__((ext_vector_type(8))) short s16x8;

// round-to-nearest-even fp32 -> bf16 bits
__device__ __forceinline__ short f2bf(float f) {
    union { float f; unsigned u; } v; v.f = f;
    unsigned r = (v.u + 0x7FFFu + ((v.u >> 16) & 1u)) >> 16;
    return (short)(unsigned short)r;
}

__global__ __launch_bounds__(256) void cvt_bf16_kernel(const float* __restrict__ in,
                                                       short* __restrict__ out, long n8) {
    long i = (long)blockIdx.x * blockDim.x + threadIdx.x;
    long stride = (long)gridDim.x * blockDim.x;
    for (; i < n8; i += stride) {
        f32x4 a = ((const f32x4*)in)[i * 2];
        f32x4 b = ((const f32x4*)in)[i * 2 + 1];
        s16x8 r;
        r[0] = f2bf(a[0]); r[1] = f2bf(a[1]); r[2] = f2bf(a[2]); r[3] = f2bf(a[3]);
        r[4] = f2bf(b[0]); r[5] = f2bf(b[1]); r[6] = f2bf(b[2]); r[7] = f2bf(b[3]);
        ((s16x8*)out)[i] = r;
    }
}

// one wave per token: logits = tanh(x @ w1^T) @ w2^T, top-2, softmax
__global__ __launch_bounds__(256) void gate_kernel(
    const float* __restrict__ x, const float* __restrict__ w1, const float* __restrict__ w2,
    int* __restrict__ tok_list, float* __restrict__ score_list, int* __restrict__ cnt,
    int* __restrict__ tk_idx, float* __restrict__ tk_score)
{
    const int lane = threadIdx.x & 63;
    const int wid = threadIdx.x >> 6;
    const int t = blockIdx.x * 4 + wid;
    const float* xt = x + (long)t * DD;

    float acc[8] = {0.f,0.f,0.f,0.f,0.f,0.f,0.f,0.f};
#pragma unroll
    for (int i = 0; i < DD / 256; ++i) {
        f32x4 xv = *(const f32x4*)&xt[i * 256 + lane * 4];
#pragma unroll
        for (int e2 = 0; e2 < 8; ++e2) {
            f32x4 wv = *(const f32x4*)&w1[e2 * DD + i * 256 + lane * 4];
            acc[e2] += xv[0]*wv[0] + xv[1]*wv[1] + xv[2]*wv[2] + xv[3]*wv[3];
        }
    }
#pragma unroll
    for (int e2 = 0; e2 < 8; ++e2) {
#pragma unroll
        for (int off = 32; off > 0; off >>= 1)
            acc[e2] += __shfl_xor(acc[e2], off, 64);
    }

    float th[8], lg[8];
#pragma unroll
    for (int e2 = 0; e2 < 8; ++e2) th[e2] = tanhf(acc[e2]);
#pragma unroll
    for (int eo = 0; eo < 8; ++eo) {
        float s = 0.f;
#pragma unroll
        for (int e2 = 0; e2 < 8; ++e2) s += th[e2] * w2[eo * 8 + e2];
        lg[eo] = s;
    }
    // top-2 (ties -> lowest index, matching jax.lax.top_k)
    int e0 = 0;
#pragma unroll
    for (int q = 1; q < 8; ++q) if (lg[q] > lg[e0]) e0 = q;
    int e1 = (e0 == 0) ? 1 : 0;
#pragma unroll
    for (int q = 0; q < 8; ++q) if (q != e0 && lg[q] > lg[e1]) e1 = q;

    float d = expf(lg[e1] - lg[e0]);
    float s0 = 1.f / (1.f + d);
    float s1 = d / (1.f + d);

    if (lane == 0) {
        tk_idx[t * 2] = e0; tk_idx[t * 2 + 1] = e1;
        tk_score[t * 2] = s0; tk_score[t * 2 + 1] = s1;
        int p0 = atomicAdd(&cnt[e0], 1);
        tok_list[e0 * TT + p0] = t; score_list[e0 * TT + p0] = s0;
        int p1 = atomicAdd(&cnt[e1], 1);
        tok_list[e1 * TT + p1] = t; score_list[e1 * TT + p1] = s1;
    }
}

// single block, deterministic fixed-tree reduction -> cv^2 balance loss
__global__ __launch_bounds__(256) void loss_kernel(const int* __restrict__ tk_idx,
                                                   const float* __restrict__ tk_score,
                                                   float* __restrict__ loss_out)
{
    __shared__ float simp[8][256];
    __shared__ float sload[8][256];
    const int tid = threadIdx.x;
    float imp[8] = {0.f,0.f,0.f,0.f,0.f,0.f,0.f,0.f};
    float ld[8]  = {0.f,0.f,0.f,0.f,0.f,0.f,0.f,0.f};
    for (int s = tid; s < TT * 2; s += 256) {
        int e = tk_idx[s];
        float sc = tk_score[s];
#pragma unroll
        for (int q = 0; q < 8; ++q) {
            bool m = (q == e);
            imp[q] += m ? sc : 0.f;
            ld[q]  += m ? 1.f : 0.f;
        }
    }
#pragma unroll
    for (int q = 0; q < 8; ++q) { simp[q][tid] = imp[q]; sload[q][tid] = ld[q]; }
    __syncthreads();
    for (int off = 128; off > 0; off >>= 1) {
        if (tid < off) {
#pragma unroll
            for (int q = 0; q < 8; ++q) {
                simp[q][tid] += simp[q][tid + off];
                sload[q][tid] += sload[q][tid + off];
            }
        }
        __syncthreads();
    }
    if (tid == 0) {
        float mi = 0.f, ml = 0.f;
#pragma unroll
        for (int q = 0; q < 8; ++q) { mi += simp[q][0]; ml += sload[q][0]; }
        mi *= 0.125f; ml *= 0.125f;
        float vi = 0.f, vl = 0.f;
#pragma unroll
        for (int q = 0; q < 8; ++q) {
            float a = simp[q][0] - mi; vi += a * a;
            float b = sload[q][0] - ml; vl += b * b;
        }
        vi /= 7.f; vl /= 7.f;
        float cvi = vi / (mi * mi + 1e-10f);
        float cvl = vl / (ml * ml + 1e-10f);
        loss_out[0] = 0.01f * (cvi + cvl);
    }
}

#define GLD16(gsrc, ldst) \
    __builtin_amdgcn_global_load_lds((const __attribute__((address_space(1))) unsigned int*)(gsrc), \
                                     (__attribute__((address_space(3))) unsigned int*)(ldst), 16, 0, 0)

// grouped GEMM: per (expert, 128-token tile, 128-out tile); gathered A rows
__global__ __launch_bounds__(256) void moe_gemm(
    const short* __restrict__ xbf, const short* __restrict__ wbf,
    const float* __restrict__ eb,
    const int* __restrict__ tok_list, const float* __restrict__ score_list,
    const int* __restrict__ cnt, float* __restrict__ y)
{
    const int e = blockIdx.z;
    const int n_e = cnt[e];
    const int row0 = blockIdx.y * 128;
    if (row0 >= n_e) return;
    const int col0 = blockIdx.x * 128;

    __shared__ short As[128 * 64];   // [token-slot][k]
    __shared__ short Bs[128 * 64];   // [out-col][k]  (W rows are contiguous in D)
    __shared__ int   stok[128];
    __shared__ float ssc[128];

    const int tid = threadIdx.x;
    const int lane = tid & 63;
    const int wid = tid >> 6;

    if (tid < 128) {
        int slot = row0 + tid;
        if (slot >= n_e) slot = n_e - 1;   // pad rows clamp (stores predicated off)
        stok[tid] = tok_list[e * TT + slot];
        ssc[tid]  = score_list[e * TT + slot];
    }
    __syncthreads();

    // staging: 1024 16B-chunks per tile; chunk q = i*256 + tid; row = q>>3, col8 = (q&7)*8
    const short* aSrc[4];
    const short* bSrc[4];
#pragma unroll
    for (int i = 0; i < 4; ++i) {
        int q = i * 256 + tid;
        int r = q >> 3;
        int c = (q & 7) * 8;
        aSrc[i] = xbf + (long)stok[r] * DD + c;
        bSrc[i] = wbf + (long)e * OO * DD + (long)(col0 + r) * DD + c;
    }

    f32x4 acc[4][4];
#pragma unroll
    for (int m = 0; m < 4; ++m)
#pragma unroll
        for (int n = 0; n < 4; ++n) acc[m][n] = f32x4{0.f, 0.f, 0.f, 0.f};

    const int wr = wid >> 1, wc = wid & 1;      // 2x2 waves, 64x64 each
    const int fr = lane & 15, fq = lane >> 4;
    const int aOff = (wr * 64 + fr) * 64 + fq * 8;
    const int bOff = (wc * 64 + fr) * 64 + fq * 8;

    for (int k0 = 0; k0 < DD; k0 += 64) {
#pragma unroll
        for (int i = 0; i < 4; ++i) {
            GLD16(aSrc[i] + k0, &As[i * 2048 + wid * 512]);
            GLD16(bSrc[i] + k0, &Bs[i * 2048 + wid * 512]);
        }
        __syncthreads();

        s16x8 af[4][2], bf_[4][2];
#pragma unroll
        for (int m = 0; m < 4; ++m)
#pragma unroll
            for (int kk = 0; kk < 2; ++kk)
                af[m][kk] = *(const s16x8*)&As[aOff + m * 16 * 64 + kk * 32];
#pragma unroll
        for (int n = 0; n < 4; ++n)
#pragma unroll
            for (int kk = 0; kk < 2; ++kk)
                bf_[n][kk] = *(const s16x8*)&Bs[bOff + n * 16 * 64 + kk * 32];

#pragma unroll
        for (int m = 0; m < 4; ++m)
#pragma unroll
            for (int n = 0; n < 4; ++n)
#pragma unroll
                for (int kk = 0; kk < 2; ++kk)
                    acc[m][n] = __builtin_amdgcn_mfma_f32_16x16x32_bf16(
                        af[m][kk], bf_[n][kk], acc[m][n], 0, 0, 0);
        __syncthreads();
    }

    float bval[4];
#pragma unroll
    for (int n = 0; n < 4; ++n)
        bval[n] = eb[e * OO + col0 + wc * 64 + n * 16 + fr];

    // C/D layout: col = lane&15, row = (lane>>4)*4 + j  [m89/m91-verified]
#pragma unroll
    for (int m = 0; m < 4; ++m) {
#pragma unroll
        for (int j = 0; j < 4; ++j) {
            int tslot = wr * 64 + m * 16 + fq * 4 + j;
            if (row0 + tslot < n_e) {
                int t = stok[tslot];
                float s = ssc[tslot];
#pragma unroll
                for (int n = 0; n < 4; ++n) {
                    int o = col0 + wc * 64 + n * 16 + fr;
                    atomicAdd(&y[(long)t * OO + o], s * (acc[m][n][j] + bval[n]));
                }
            }
        }
    }
}

extern "C" void kernel_launch(void* const* d_in, const int* in_sizes, int n_in,
                              void* d_out, int out_size, void* d_ws, size_t ws_size,
                              hipStream_t stream) {
    const float* x  = (const float*)d_in[0];
    const float* w1 = (const float*)d_in[1];
    const float* w2 = (const float*)d_in[2];
    const float* ew = (const float*)d_in[3];
    const float* eb = (const float*)d_in[4];
    float* y = (float*)d_out;   // [T*O] then gate_loss at [T*O]

    char* ws = (char*)d_ws;
    short* xbf = (short*)ws;            ws += (size_t)TT * DD * 2;
    short* wbf = (short*)ws;            ws += (size_t)EE * OO * DD * 2;
    int*   tok_list = (int*)ws;         ws += (size_t)EE * TT * 4;
    float* score_list = (float*)ws;     ws += (size_t)EE * TT * 4;
    int*   tk_idx = (int*)ws;           ws += (size_t)TT * 2 * 4;
    float* tk_score = (float*)ws;       ws += (size_t)TT * 2 * 4;
    int*   cnt = (int*)ws;              ws += 64;

    // zero accumulators every call (harness does not re-poison between replays)
    hipMemsetAsync(cnt, 0, 32, stream);
    hipMemsetAsync(d_out, 0, (size_t)TT * OO * sizeof(float), stream);

    cvt_bf16_kernel<<<2048, 256, 0, stream>>>(x,  xbf, (long)TT * DD / 8);
    cvt_bf16_kernel<<<4096, 256, 0, stream>>>(ew, wbf, (long)EE * OO * DD / 8);
    gate_kernel<<<TT / 4, 256, 0, stream>>>(x, w1, w2, tok_list, score_list, cnt,
                                            tk_idx, tk_score);
    loss_kernel<<<1, 256, 0, stream>>>(tk_idx, tk_score, y + (size_t)TT * OO);
    moe_gemm<<<dim3(OO / 128, TT / 128, EE), 256, 0, stream>>>(
        xbf, wbf, eb, tok_list, score_list, cnt, y);
}

// Round 2
// 386.793 us; speedup vs baseline: 1.5432x; 1.5432x over previous
//
#include <hip/hip_runtime.h>
#include <hip/hip_bf16.h>

#define TT 8192
#define DD 2048
#define OO 2048
#define EE 8

typedef __attribute__((ext_vector_type(4))) float f32x4;
typedef __attribute__((ext_vector_type(8))) short s16x8;

// round-to-nearest-even fp32 -> bf16 bits
__device__ __forceinline__ short f2bf(float f) {
    union { float f; unsigned u; } v; v.f = f;
    unsigned r = (v.u + 0x7FFFu + ((v.u >> 16) & 1u)) >> 16;
    return (short)(unsigned short)r;
}

__global__ __launch_bounds__(256) void cvt_bf16_kernel(const float* __restrict__ in,
                                                       short* __restrict__ out, long n8) {
    long i = (long)blockIdx.x * blockDim.x + threadIdx.x;
    long stride = (long)gridDim.x * blockDim.x;
    for (; i < n8; i += stride) {
        f32x4 a = ((const f32x4*)in)[i * 2];
        f32x4 b = ((const f32x4*)in)[i * 2 + 1];
        s16x8 r;
        r[0] = f2bf(a[0]); r[1] = f2bf(a[1]); r[2] = f2bf(a[2]); r[3] = f2bf(a[3]);
        r[4] = f2bf(b[0]); r[5] = f2bf(b[1]); r[6] = f2bf(b[2]); r[7] = f2bf(b[3]);
        ((s16x8*)out)[i] = r;
    }
}

// one wave per token: logits = tanh(x @ w1^T) @ w2^T, top-2, softmax.
// No atomics -- just writes per-token top-2 indices and scores.
__global__ __launch_bounds__(256) void gate_kernel(
    const float* __restrict__ x, const float* __restrict__ w1, const float* __restrict__ w2,
    int* __restrict__ tk_idx, float* __restrict__ tk_score)
{
    const int lane = threadIdx.x & 63;
    const int wid = threadIdx.x >> 6;
    const int t = blockIdx.x * 4 + wid;
    const float* xt = x + (long)t * DD;

    float acc[8] = {0.f,0.f,0.f,0.f,0.f,0.f,0.f,0.f};
#pragma unroll
    for (int i = 0; i < DD / 256; ++i) {
        f32x4 xv = *(const f32x4*)&xt[i * 256 + lane * 4];
#pragma unroll
        for (int e2 = 0; e2 < 8; ++e2) {
            f32x4 wv = *(const f32x4*)&w1[e2 * DD + i * 256 + lane * 4];
            acc[e2] += xv[0]*wv[0] + xv[1]*wv[1] + xv[2]*wv[2] + xv[3]*wv[3];
        }
    }
#pragma unroll
    for (int e2 = 0; e2 < 8; ++e2) {
#pragma unroll
        for (int off = 32; off > 0; off >>= 1)
            acc[e2] += __shfl_xor(acc[e2], off, 64);
    }

    float th[8], lg[8];
#pragma unroll
    for (int e2 = 0; e2 < 8; ++e2) th[e2] = tanhf(acc[e2]);
#pragma unroll
    for (int eo = 0; eo < 8; ++eo) {
        float s = 0.f;
#pragma unroll
        for (int e2 = 0; e2 < 8; ++e2) s += th[e2] * w2[eo * 8 + e2];
        lg[eo] = s;
    }
    // top-2 (ties -> lowest index, matching jax.lax.top_k)
    int e0 = 0;
#pragma unroll
    for (int q = 1; q < 8; ++q) if (lg[q] > lg[e0]) e0 = q;
    int e1 = (e0 == 0) ? 1 : 0;
#pragma unroll
    for (int q = 0; q < 8; ++q) if (q != e0 && lg[q] > lg[e1]) e1 = q;

    float d = expf(lg[e1] - lg[e0]);
    float s0 = 1.f / (1.f + d);
    float s1 = d / (1.f + d);

    if (lane == 0) {
        tk_idx[t * 2] = e0; tk_idx[t * 2 + 1] = e1;
        tk_score[t * 2] = s0; tk_score[t * 2 + 1] = s1;
    }
}

// one block per expert: deterministic token-order compaction via ballot prefix scan
__global__ __launch_bounds__(256) void build_lists(
    const int* __restrict__ tk_idx, const float* __restrict__ tk_score,
    int* __restrict__ tok_list, float* __restrict__ score_list, int* __restrict__ cnt)
{
    const int e = blockIdx.x;
    const int lane = threadIdx.x & 63;
    const int wid = threadIdx.x >> 6;
    __shared__ int wsum[4];
    int base = 0;
    for (int t0 = 0; t0 < TT; t0 += 256) {
        int t = t0 + threadIdx.x;
        int i0 = tk_idx[t * 2], i1 = tk_idx[t * 2 + 1];
        bool has = (i0 == e) || (i1 == e);
        float sc = (i0 == e) ? tk_score[t * 2] : tk_score[t * 2 + 1];
        unsigned long long m = __ballot(has);
        int prefix = __popcll(m & ((1ull << lane) - 1ull));
        if (lane == 0) wsum[wid] = __popcll(m);
        __syncthreads();
        int woff = 0;
#pragma unroll
        for (int w = 0; w < 4; ++w) woff += (w < wid) ? wsum[w] : 0;
        int total = wsum[0] + wsum[1] + wsum[2] + wsum[3];
        if (has) {
            int p = base + woff + prefix;
            tok_list[e * TT + p] = t;
            score_list[e * TT + p] = sc;
        }
        base += total;
        __syncthreads();
    }
    if (threadIdx.x == 0) cnt[e] = base;
}

// single block, deterministic fixed-tree reduction -> cv^2 balance loss
__global__ __launch_bounds__(256) void loss_kernel(const int* __restrict__ tk_idx,
                                                   const float* __restrict__ tk_score,
                                                   float* __restrict__ loss_out)
{
    __shared__ float simp[8][256];
    __shared__ float sload[8][256];
    const int tid = threadIdx.x;
    float imp[8] = {0.f,0.f,0.f,0.f,0.f,0.f,0.f,0.f};
    float ld[8]  = {0.f,0.f,0.f,0.f,0.f,0.f,0.f,0.f};
    for (int s = tid; s < TT * 2; s += 256) {
        int e = tk_idx[s];
        float sc = tk_score[s];
#pragma unroll
        for (int q = 0; q < 8; ++q) {
            bool m = (q == e);
            imp[q] += m ? sc : 0.f;
            ld[q]  += m ? 1.f : 0.f;
        }
    }
#pragma unroll
    for (int q = 0; q < 8; ++q) { simp[q][tid] = imp[q]; sload[q][tid] = ld[q]; }
    __syncthreads();
    for (int off = 128; off > 0; off >>= 1) {
        if (tid < off) {
#pragma unroll
            for (int q = 0; q < 8; ++q) {
                simp[q][tid] += simp[q][tid + off];
                sload[q][tid] += sload[q][tid + off];
            }
        }
        __syncthreads();
    }
    if (tid == 0) {
        float mi = 0.f, ml = 0.f;
#pragma unroll
        for (int q = 0; q < 8; ++q) { mi += simp[q][0]; ml += sload[q][0]; }
        mi *= 0.125f; ml *= 0.125f;
        float vi = 0.f, vl = 0.f;
#pragma unroll
        for (int q = 0; q < 8; ++q) {
            float a = simp[q][0] - mi; vi += a * a;
            float b = sload[q][0] - ml; vl += b * b;
        }
        vi /= 7.f; vl /= 7.f;
        float cvi = vi / (mi * mi + 1e-10f);
        float cvl = vl / (ml * ml + 1e-10f);
        loss_out[0] = 0.01f * (cvi + cvl);
    }
}

#define GLD16(gsrc, ldst) \
    __builtin_amdgcn_global_load_lds((const __attribute__((address_space(1))) unsigned int*)(gsrc), \
                                     (__attribute__((address_space(3))) unsigned int*)(ldst), 16, 0, 0)

// grouped GEMM: per (expert, 128-token tile, 128-out tile); gathered A rows.
// T2-style chunk-XOR swizzle: LDS dest stays linear (global_load_lds requirement);
// the global SOURCE chunk is pre-swizzled (c = p ^ (r&7)) and the ds_read applies
// the same XOR -- both-sides-or-neither (rule #21).
__global__ __launch_bounds__(256) void moe_gemm(
    const short* __restrict__ xbf, const short* __restrict__ wbf,
    const float* __restrict__ eb,
    const int* __restrict__ tok_list, const float* __restrict__ score_list,
    const int* __restrict__ cnt, float* __restrict__ y)
{
    const int e = blockIdx.z;
    const int n_e = cnt[e];
    const int row0 = blockIdx.y * 128;
    if (row0 >= n_e) return;
    const int col0 = blockIdx.x * 128;

    __shared__ short As[128 * 64];   // [token-slot][k], chunk-swizzled
    __shared__ short Bs[128 * 64];   // [out-col][k],   chunk-swizzled
    __shared__ int   stok[128];
    __shared__ float ssc[128];

    const int tid = threadIdx.x;
    const int lane = tid & 63;
    const int wid = tid >> 6;

    if (tid < 128) {
        int slot = row0 + tid;
        if (slot >= n_e) slot = n_e - 1;   // pad rows clamp (stores predicated off)
        stok[tid] = tok_list[e * TT + slot];
        ssc[tid]  = score_list[e * TT + slot];
    }
    __syncthreads();

    // staging: 1024 16B-chunks per tile; LDS chunk q = i*256+tid (linear dest);
    // physical chunk p at row r holds logical chunk p ^ (r&7)
    const short* aSrc[4];
    const short* bSrc[4];
#pragma unroll
    for (int i = 0; i < 4; ++i) {
        int q = i * 256 + tid;
        int r = q >> 3;
        int c = (q & 7) ^ (r & 7);    // swizzled source chunk
        aSrc[i] = xbf + (long)stok[r] * DD + c * 8;
        bSrc[i] = wbf + (long)e * OO * DD + (long)(col0 + r) * DD + c * 8;
    }

    f32x4 acc[4][4];
#pragma unroll
    for (int m = 0; m < 4; ++m)
#pragma unroll
        for (int n = 0; n < 4; ++n) acc[m][n] = f32x4{0.f, 0.f, 0.f, 0.f};

    const int wr = wid >> 1, wc = wid & 1;      // 2x2 waves, 64x64 each
    const int fr = lane & 15, fq = lane >> 4;
    // swizzled read chunk offsets (lane-constant): logical chunk fq + kk*4
    const int sw0 = ((fq + 0) ^ (fr & 7)) * 8;
    const int sw1 = ((fq + 4) ^ (fr & 7)) * 8;
    const int aRow = (wr * 64 + fr) * 64;
    const int bRow = (wc * 64 + fr) * 64;

    for (int k0 = 0; k0 < DD; k0 += 64) {
#pragma unroll
        for (int i = 0; i < 4; ++i) {
            GLD16(aSrc[i] + k0, &As[i * 2048 + wid * 512]);
            GLD16(bSrc[i] + k0, &Bs[i * 2048 + wid * 512]);
        }
        __syncthreads();

        s16x8 af[4][2], bf_[4][2];
#pragma unroll
        for (int m = 0; m < 4; ++m) {
            af[m][0] = *(const s16x8*)&As[aRow + m * 16 * 64 + sw0];
            af[m][1] = *(const s16x8*)&As[aRow + m * 16 * 64 + sw1];
        }
#pragma unroll
        for (int n = 0; n < 4; ++n) {
            bf_[n][0] = *(const s16x8*)&Bs[bRow + n * 16 * 64 + sw0];
            bf_[n][1] = *(const s16x8*)&Bs[bRow + n * 16 * 64 + sw1];
        }

#pragma unroll
        for (int m = 0; m < 4; ++m)
#pragma unroll
            for (int n = 0; n < 4; ++n)
#pragma unroll
                for (int kk = 0; kk < 2; ++kk)
                    acc[m][n] = __builtin_amdgcn_mfma_f32_16x16x32_bf16(
                        af[m][kk], bf_[n][kk], acc[m][n], 0, 0, 0);
        __syncthreads();
    }

    float bval[4];
#pragma unroll
    for (int n = 0; n < 4; ++n)
        bval[n] = eb[e * OO + col0 + wc * 64 + n * 16 + fr];

    // C/D layout: col = lane&15, row = (lane>>4)*4 + j  [m89/m91-verified]
#pragma unroll
    for (int m = 0; m < 4; ++m) {
#pragma unroll
        for (int j = 0; j < 4; ++j) {
            int tslot = wr * 64 + m * 16 + fq * 4 + j;
            if (row0 + tslot < n_e) {
                int t = stok[tslot];
                float s = ssc[tslot];
#pragma unroll
                for (int n = 0; n < 4; ++n) {
                    int o = col0 + wc * 64 + n * 16 + fr;
                    atomicAdd(&y[(long)t * OO + o], s * (acc[m][n][j] + bval[n]));
                }
            }
        }
    }
}

extern "C" void kernel_launch(void* const* d_in, const int* in_sizes, int n_in,
                              void* d_out, int out_size, void* d_ws, size_t ws_size,
                              hipStream_t stream) {
    const float* x  = (const float*)d_in[0];
    const float* w1 = (const float*)d_in[1];
    const float* w2 = (const float*)d_in[2];
    const float* ew = (const float*)d_in[3];
    const float* eb = (const float*)d_in[4];
    float* y = (float*)d_out;   // [T*O] then gate_loss at [T*O]

    char* ws = (char*)d_ws;
    short* xbf = (short*)ws;            ws += (size_t)TT * DD * 2;
    short* wbf = (short*)ws;            ws += (size_t)EE * OO * DD * 2;
    int*   tok_list = (int*)ws;         ws += (size_t)EE * TT * 4;
    float* score_list = (float*)ws;     ws += (size_t)EE * TT * 4;
    int*   tk_idx = (int*)ws;           ws += (size_t)TT * 2 * 4;
    float* tk_score = (float*)ws;       ws += (size_t)TT * 2 * 4;
    int*   cnt = (int*)ws;              ws += 64;

    // zero the atomic-accumulated output every call (harness does not re-poison)
    hipMemsetAsync(d_out, 0, (size_t)TT * OO * sizeof(float), stream);

    cvt_bf16_kernel<<<2048, 256, 0, stream>>>(x,  xbf, (long)TT * DD / 8);
    cvt_bf16_kernel<<<4096, 256, 0, stream>>>(ew, wbf, (long)EE * OO * DD / 8);
    gate_kernel<<<TT / 4, 256, 0, stream>>>(x, w1, w2, tk_idx, tk_score);
    build_lists<<<EE, 256, 0, stream>>>(tk_idx, tk_score, tok_list, score_list, cnt);
    loss_kernel<<<1, 256, 0, stream>>>(tk_idx, tk_score, y + (size_t)TT * OO);
    moe_gemm<<<dim3(OO / 128, TT / 128, EE), 256, 0, stream>>>(
        xbf, wbf, eb, tok_list, score_list, cnt, y);
}